// Round 2
// baseline (559.712 us; speedup 1.0000x reference)
//
#include <hip/hip_runtime.h>
#include <hip/hip_bf16.h>
#include <math.h>
#include <stdint.h>

#define BT  4096
#define DIM 1024
#define HID 4096
#define NE  8
#define TMX2 40   // max active 256-row m-blocks (32 full + 8 partial)

typedef __attribute__((ext_vector_type(8))) short short8v;
typedef __attribute__((ext_vector_type(4))) float f32x4;
typedef unsigned short ushort_t;

typedef __attribute__((address_space(1))) const void gas_void;
typedef __attribute__((address_space(3))) void las_void;
#define GLOAD_LDS16(g, l) __builtin_amdgcn_global_load_lds((gas_void*)(g), (las_void*)(l), 16, 0, 0)

__device__ inline ushort_t f2bf(float f) {
  __hip_bfloat16 b = __float2bfloat16(f);
  union { __hip_bfloat16 h; ushort_t u; } cv;
  cv.h = b;
  return cv.u;
}

// -------- prep: x fp32 -> bf16 ; zero per-expert cursors --------
__global__ void k_prep_x(const float* __restrict__ x, ushort_t* __restrict__ xbf,
                         int* __restrict__ cur) {
  if (blockIdx.x == 0 && threadIdx.x < NE) cur[threadIdx.x] = 0;
  int idx = blockIdx.x * blockDim.x + threadIdx.x;
  const int n4 = BT * DIM / 4;
  for (int i = idx; i < n4; i += gridDim.x * blockDim.x) {
    float4 v = ((const float4*)x)[i];
    ushort4 o;
    o.x = f2bf(v.x); o.y = f2bf(v.y); o.z = f2bf(v.z); o.w = f2bf(v.w);
    ((ushort4*)xbf)[i] = o;
  }
}

// -------- transpose+convert: src fp32 [E][R][C] -> dst bf16 [E][C][R] --------
__global__ __launch_bounds__(256) void k_transpose(const float* __restrict__ src,
                                                   ushort_t* __restrict__ dst,
                                                   int R, int C) {
  __shared__ float tile[64][65];
  int e = blockIdx.z;
  const float* s = src + (size_t)e * R * C;
  ushort_t* d = dst + (size_t)e * R * C;
  int c0 = blockIdx.x * 64, r0 = blockIdx.y * 64;
  int t = threadIdx.x;
  int lr = t >> 4;
  int lc4 = (t & 15) * 4;
#pragma unroll
  for (int i = 0; i < 4; i++) {
    int r = lr + 16 * i;
    float4 v = *(const float4*)&s[(size_t)(r0 + r) * C + c0 + lc4];
    tile[r][lc4 + 0] = v.x; tile[r][lc4 + 1] = v.y;
    tile[r][lc4 + 2] = v.z; tile[r][lc4 + 3] = v.w;
  }
  __syncthreads();
#pragma unroll
  for (int i = 0; i < 4; i++) {
    int c = lr + 16 * i;
    ushort4 o;
    o.x = f2bf(tile[lc4 + 0][c]);
    o.y = f2bf(tile[lc4 + 1][c]);
    o.z = f2bf(tile[lc4 + 2][c]);
    o.w = f2bf(tile[lc4 + 3][c]);
    *(ushort4*)&d[(size_t)(c0 + c) * R + r0 + lc4] = o;
  }
}

// -------- router: logits, softmax, top-2, binning --------
__global__ __launch_bounds__(64) void k_router(
    const float* __restrict__ x, const float* __restrict__ wg,
    float* __restrict__ logits_out, float* __restrict__ probs01,
    int* __restrict__ assign, int* __restrict__ cur) {
  int t = blockIdx.x;
  int lane = threadIdx.x;
  float part[NE];
#pragma unroll
  for (int e = 0; e < NE; e++) part[e] = 0.f;
  const float* xr = x + (size_t)t * DIM;
  for (int d = lane; d < DIM; d += 64) {
    float xv = xr[d];
    const float4* wr = (const float4*)(wg + (size_t)d * NE);
    float4 w0 = wr[0], w1v = wr[1];
    part[0] += xv * w0.x;  part[1] += xv * w0.y;
    part[2] += xv * w0.z;  part[3] += xv * w0.w;
    part[4] += xv * w1v.x; part[5] += xv * w1v.y;
    part[6] += xv * w1v.z; part[7] += xv * w1v.w;
  }
#pragma unroll
  for (int e = 0; e < NE; e++)
    for (int off = 32; off > 0; off >>= 1)
      part[e] += __shfl_xor(part[e], off);
  if (lane == 0) {
    float m = part[0];
    for (int e = 1; e < NE; e++) m = fmaxf(m, part[e]);
    float p[NE], s = 0.f;
    for (int e = 0; e < NE; e++) { p[e] = expf(part[e] - m); s += p[e]; }
    float inv = 1.f / s;
    for (int e = 0; e < NE; e++) p[e] *= inv;
    for (int e = 0; e < NE; e++) logits_out[(size_t)t * NE + e] = part[e];
    probs01[t * 2 + 0] = p[0];
    probs01[t * 2 + 1] = p[1];
    int b0 = 0;
    for (int e = 1; e < NE; e++) if (p[e] > p[b0]) b0 = e;
    int b1 = (b0 == 0) ? 1 : 0;
    for (int e = 0; e < NE; e++) if (e != b0 && p[e] > p[b1]) b1 = e;
    int pos0 = atomicAdd(&cur[b0], 1);
    assign[b0 * BT + pos0] = t * 2 + 0;
    int pos1 = atomicAdd(&cur[b1], 1);
    assign[b1 * BT + pos1] = t * 2 + 1;
  }
}

// -------- plan: prefix offsets + flattened active 256-row block list --------
__global__ void k_plan(const int* __restrict__ cur, int* __restrict__ segoff,
                       int* __restrict__ blk2_e, int* __restrict__ blk2_m0) {
  if (threadIdx.x == 0 && blockIdx.x == 0) {
    int s = 0;
    for (int e = 0; e < NE; e++) { segoff[e] = s; s += cur[e]; }
    int t = 0;
    for (int e = 0; e < NE; e++) {
      int mb = (cur[e] + 255) >> 8;
      for (int i = 0; i < mb; i++) { blk2_e[t] = e; blk2_m0[t] = i << 8; t++; }
    }
    for (; t < TMX2; t++) { blk2_e[t] = -1; blk2_m0[t] = 0; }
  }
}

// ============================================================================
// GEMM1: h = gelu(x_gathered @ w1^T + b1)
// 256x256 tile, BK=32, 4-deep LDS ring (128 KiB), ONE barrier per K-tile,
// counted vmcnt (never 0 in steady state), T2 XOR swizzle, T5 setprio.
// Ring safety: stage of tile t+3 (issued AFTER iter-t barrier) overwrites the
// slot read at iter t-1; all its readers are past this barrier. vmcnt(8)
// before the barrier guarantees tile t's async LDS-writes landed block-wide.
// ============================================================================
__global__ __launch_bounds__(512, 2) void k_gemm1(
    const ushort_t* __restrict__ xbf, const ushort_t* __restrict__ wt1,
    const float* __restrict__ b1,
    const int* __restrict__ assign, const int* __restrict__ cur,
    const int* __restrict__ segoff, const int* __restrict__ blk2_e,
    const int* __restrict__ blk2_m0, ushort_t* __restrict__ hbuf) {
  const int nwg = 16 * TMX2;                   // 640, divisible by 8
  int f = blockIdx.x;
  int lg = (f & 7) * (nwg >> 3) + (f >> 3);    // XCD chunk swizzle (bijective)
  int m_idx = lg % TMX2;                       // m-major inner: chunk reuses B-panels
  int n_idx = lg / TMX2;
  int e = blk2_e[m_idx];
  if (e < 0) return;
  int m0 = blk2_m0[m_idx];
  int count = cur[e];
  int n0 = n_idx << 8;

  __shared__ __attribute__((aligned(16))) ushort_t A[4][256][32];
  __shared__ __attribute__((aligned(16))) ushort_t Bv[4][256][32];
  int tid = threadIdx.x;
  int lane = tid & 63, wid = tid >> 6;

  // staging: each gload call = 128 rows; wave writes 16 rows (4 lanes/row).
  // physical 16B-unit = lane&3; source logical unit = (lane&3) ^ (row&3).
  int srow = lane >> 2;
  int sunit = ((lane & 3) ^ (srow & 3)) << 3;  // bf16 elems
  int pA0 = m0 + wid * 16 + srow;
  int pA1 = pA0 + 128;
  int tok0 = (pA0 < count) ? (assign[e * BT + pA0] >> 1) : 0;
  int tok1 = (pA1 < count) ? (assign[e * BT + pA1] >> 1) : 0;
  const ushort_t* gA0 = xbf + (size_t)tok0 * DIM + sunit;
  const ushort_t* gA1 = xbf + (size_t)tok1 * DIM + sunit;
  const ushort_t* gB0 = wt1 + ((size_t)e * HID + n0 + wid * 16 + srow) * DIM + sunit;
  const ushort_t* gB1 = gB0 + (size_t)128 * DIM;

  int wm = wid >> 2, wn = wid & 3;             // wave tile: 128(m) x 64(n)
  int lr = lane & 15, g = lane >> 4;
  int xsw = ((g ^ (lr & 3)) << 3);             // swizzled read offset (elems)
  f32x4 acc[8][4];
  f32x4 zero = {0.f, 0.f, 0.f, 0.f};
#pragma unroll
  for (int m = 0; m < 8; m++)
#pragma unroll
    for (int n = 0; n < 4; n++) acc[m][n] = zero;

#define STAGE1(TB, K0)                                         \
  { GLOAD_LDS16(gA0 + (K0), &A[TB][wid * 16][0]);              \
    GLOAD_LDS16(gA1 + (K0), &A[TB][128 + wid * 16][0]);        \
    GLOAD_LDS16(gB0 + (K0), &Bv[TB][wid * 16][0]);             \
    GLOAD_LDS16(gB1 + (K0), &Bv[TB][128 + wid * 16][0]); }

#define BODY1(T, TB, VM, DOSTAGE)                                              \
  { asm volatile("s_waitcnt vmcnt(" #VM ")" ::: "memory");                     \
    __builtin_amdgcn_s_barrier();                                              \
    __builtin_amdgcn_sched_barrier(0);                                         \
    if (DOSTAGE) { STAGE1((((TB) + 3) & 3), ((T) + 3) * 32); }                 \
    short8v af[8], bfv[4];                                                     \
    _Pragma("unroll")                                                          \
    for (int m = 0; m < 8; m++)                                                \
      af[m] = *(const short8v*)&A[TB][wm * 128 + m * 16 + lr][xsw];            \
    _Pragma("unroll")                                                          \
    for (int n = 0; n < 4; n++)                                                \
      bfv[n] = *(const short8v*)&Bv[TB][wn * 64 + n * 16 + lr][xsw];           \
    __builtin_amdgcn_s_setprio(1);                                             \
    _Pragma("unroll")                                                          \
    for (int m = 0; m < 8; m++)                                                \
      _Pragma("unroll")                                                        \
      for (int n = 0; n < 4; n++)                                              \
        acc[m][n] = __builtin_amdgcn_mfma_f32_16x16x32_bf16(af[m], bfv[n],     \
                                                            acc[m][n], 0, 0, 0); \
    __builtin_amdgcn_s_setprio(0); }

  // prologue: 3 tiles in flight
  STAGE1(0, 0);
  STAGE1(1, 32);
  STAGE1(2, 64);
  const int NT = DIM / 32;                     // 32
  for (int t = 0; t < NT - 4; t += 4) {
    BODY1(t + 0, 0, 8, 1);
    BODY1(t + 1, 1, 8, 1);
    BODY1(t + 2, 2, 8, 1);
    BODY1(t + 3, 3, 8, 1);
  }
  BODY1(NT - 4, 0, 8, 1);
  BODY1(NT - 3, 1, 8, 0);
  BODY1(NT - 2, 2, 4, 0);
  BODY1(NT - 1, 3, 0, 0);
#undef STAGE1
#undef BODY1

  int so = segoff[e];
#pragma unroll
  for (int m = 0; m < 8; m++) {
#pragma unroll
    for (int j = 0; j < 4; j++) {
      int p = m0 + wm * 128 + m * 16 + g * 4 + j;
      if (p >= count) continue;
      ushort_t* hr = hbuf + (size_t)(so + p) * HID;
#pragma unroll
      for (int n = 0; n < 4; n++) {
        int col = n0 + wn * 64 + n * 16 + lr;
        float v = acc[m][n][j] + b1[e * HID + col];
        float gl = 0.5f * v * (1.0f + erff(v * 0.70710678118654752f));
        hr[col] = f2bf(gl);
      }
    }
  }
}

// ============================================================================
// GEMM2: contrib[slot][t] = h @ w2^T + b2
// 256x128 tile, BK=32, 4-deep LDS ring (96 KiB), same counted-vmcnt schedule.
// 8 waves as 4M x 2N (wave tile 64x64). 3 gloads/tile -> vmcnt(6) steady.
// ============================================================================
__global__ __launch_bounds__(512, 2) void k_gemm2(
    const ushort_t* __restrict__ hbuf, const ushort_t* __restrict__ wt2,
    const float* __restrict__ b2,
    const int* __restrict__ assign, const int* __restrict__ cur,
    const int* __restrict__ segoff, const int* __restrict__ blk2_e,
    const int* __restrict__ blk2_m0, float* __restrict__ contrib) {
  const int nwg = 8 * TMX2;                    // 320, divisible by 8
  int f = blockIdx.x;
  int lg = (f & 7) * (nwg >> 3) + (f >> 3);
  int m_idx = lg % TMX2;
  int n_idx = lg / TMX2;
  int e = blk2_e[m_idx];
  if (e < 0) return;
  int m0 = blk2_m0[m_idx];
  int count = cur[e];
  int n0 = n_idx << 7;
  int so = segoff[e];

  __shared__ __attribute__((aligned(16))) ushort_t A[4][256][32];
  __shared__ __attribute__((aligned(16))) ushort_t Bv[4][128][32];
  int tid = threadIdx.x;
  int lane = tid & 63, wid = tid >> 6;

  int srow = lane >> 2;
  int sunit = ((lane & 3) ^ (srow & 3)) << 3;
  int pA0 = m0 + wid * 16 + srow;
  int pA1 = pA0 + 128;
  int pa0 = (pA0 < count) ? pA0 : (count - 1);
  int pa1 = (pA1 < count) ? pA1 : (count - 1);
  const ushort_t* gA0 = hbuf + (size_t)(so + pa0) * HID + sunit;
  const ushort_t* gA1 = hbuf + (size_t)(so + pa1) * HID + sunit;
  const ushort_t* gB0 = wt2 + ((size_t)e * DIM + n0 + wid * 16 + srow) * HID + sunit;

  int wm = wid >> 1, wn = wid & 1;             // wave tile: 64(m) x 64(n)
  int lr = lane & 15, g = lane >> 4;
  int xsw = ((g ^ (lr & 3)) << 3);
  f32x4 acc[4][4];
  f32x4 zero = {0.f, 0.f, 0.f, 0.f};
#pragma unroll
  for (int m = 0; m < 4; m++)
#pragma unroll
    for (int n = 0; n < 4; n++) acc[m][n] = zero;

#define STAGE2(TB, K0)                                         \
  { GLOAD_LDS16(gA0 + (K0), &A[TB][wid * 16][0]);              \
    GLOAD_LDS16(gA1 + (K0), &A[TB][128 + wid * 16][0]);        \
    GLOAD_LDS16(gB0 + (K0), &Bv[TB][wid * 16][0]); }

#define BODY2(T, TB, VM, DOSTAGE)                                              \
  { asm volatile("s_waitcnt vmcnt(" #VM ")" ::: "memory");                     \
    __builtin_amdgcn_s_barrier();                                              \
    __builtin_amdgcn_sched_barrier(0);                                         \
    if (DOSTAGE) { STAGE2((((TB) + 3) & 3), ((T) + 3) * 32); }                 \
    short8v af[4], bfv[4];                                                     \
    _Pragma("unroll")                                                          \
    for (int m = 0; m < 4; m++)                                                \
      af[m] = *(const short8v*)&A[TB][wm * 64 + m * 16 + lr][xsw];             \
    _Pragma("unroll")                                                          \
    for (int n = 0; n < 4; n++)                                                \
      bfv[n] = *(const short8v*)&Bv[TB][wn * 64 + n * 16 + lr][xsw];           \
    __builtin_amdgcn_s_setprio(1);                                             \
    _Pragma("unroll")                                                          \
    for (int m = 0; m < 4; m++)                                                \
      _Pragma("unroll")                                                        \
      for (int n = 0; n < 4; n++)                                              \
        acc[m][n] = __builtin_amdgcn_mfma_f32_16x16x32_bf16(af[m], bfv[n],     \
                                                            acc[m][n], 0, 0, 0); \
    __builtin_amdgcn_s_setprio(0); }

  STAGE2(0, 0);
  STAGE2(1, 32);
  STAGE2(2, 64);
  const int NT = HID / 32;                     // 128
  for (int t = 0; t < NT - 4; t += 4) {
    BODY2(t + 0, 0, 6, 1);
    BODY2(t + 1, 1, 6, 1);
    BODY2(t + 2, 2, 6, 1);
    BODY2(t + 3, 3, 6, 1);
  }
  BODY2(NT - 4, 0, 6, 1);
  BODY2(NT - 3, 1, 6, 0);
  BODY2(NT - 2, 2, 3, 0);
  BODY2(NT - 1, 3, 0, 0);
#undef STAGE2
#undef BODY2

#pragma unroll
  for (int m = 0; m < 4; m++) {
#pragma unroll
    for (int j = 0; j < 4; j++) {
      int p = m0 + wm * 64 + m * 16 + g * 4 + j;
      if (p >= count) continue;
      int a = assign[e * BT + p];
      int t = a >> 1, slot = a & 1;
      float* cr = contrib + ((size_t)slot * BT + t) * DIM;
#pragma unroll
      for (int n = 0; n < 4; n++) {
        int col = n0 + wn * 64 + n * 16 + lr;
        cr[col] = acc[m][n][j] + b2[e * DIM + col];
      }
    }
  }
}

// -------- combine: final = c0*probs[:,0] + c1*probs[:,1] --------
__global__ void k_combine(const float* __restrict__ contrib,
                          const float* __restrict__ probs01,
                          float* __restrict__ out) {
  int idx = blockIdx.x * blockDim.x + threadIdx.x;
  const int n4 = BT * DIM / 4;
  if (idx >= n4) return;
  int t = idx >> 8;
  float wA = probs01[t * 2 + 0], wB = probs01[t * 2 + 1];
  float4 c0 = ((const float4*)contrib)[idx];
  float4 c1 = ((const float4*)(contrib + (size_t)BT * DIM))[idx];
  float4 o;
  o.x = c0.x * wA + c1.x * wB;
  o.y = c0.y * wA + c1.y * wB;
  o.z = c0.z * wA + c1.z * wB;
  o.w = c0.w * wA + c1.w * wB;
  ((float4*)out)[idx] = o;
}

extern "C" void kernel_launch(void* const* d_in, const int* in_sizes, int n_in,
                              void* d_out, int out_size, void* d_ws, size_t ws_size,
                              hipStream_t stream) {
  const float* x  = (const float*)d_in[0];
  const float* wg = (const float*)d_in[1];
  const float* w1 = (const float*)d_in[2];
  const float* b1 = (const float*)d_in[3];
  const float* w2 = (const float*)d_in[4];
  const float* b2 = (const float*)d_in[5];
  float* out = (float*)d_out;
  float* logits_out = out + (size_t)BT * DIM;

  char* ws = (char*)d_ws;
  size_t off = 0;
  auto alloc = [&](size_t bytes) -> void* {
    void* p = ws + off;
    off = (off + bytes + 255) & ~(size_t)255;
    return p;
  };
  ushort_t* xbf    = (ushort_t*)alloc((size_t)BT * DIM * 2);
  ushort_t* wt1    = (ushort_t*)alloc((size_t)NE * HID * DIM * 2);
  ushort_t* wt2    = (ushort_t*)alloc((size_t)NE * DIM * HID * 2);
  ushort_t* hbuf   = (ushort_t*)alloc((size_t)2 * BT * HID * 2);
  float*    contrib= (float*)alloc((size_t)2 * BT * DIM * 4);
  float*    probs01= (float*)alloc((size_t)BT * 2 * 4);
  int*      assign = (int*)alloc((size_t)NE * BT * 4);
  int*      cur    = (int*)alloc(64);
  int*      segoff = (int*)alloc(64);
  int*      blk2_e = (int*)alloc(TMX2 * 4);
  int*      blk2_m0= (int*)alloc(TMX2 * 4);
  if (off > ws_size) return;

  hipLaunchKernelGGL(k_prep_x, dim3(1024), dim3(256), 0, stream, x, xbf, cur);
  hipLaunchKernelGGL(k_transpose, dim3(HID / 64, DIM / 64, NE), dim3(256), 0, stream,
                     w1, wt1, DIM, HID);
  hipLaunchKernelGGL(k_transpose, dim3(DIM / 64, HID / 64, NE), dim3(256), 0, stream,
                     w2, wt2, HID, DIM);
  hipLaunchKernelGGL(k_router, dim3(BT), dim3(64), 0, stream,
                     x, wg, logits_out, probs01, assign, cur);
  hipLaunchKernelGGL(k_plan, dim3(1), dim3(1), 0, stream, cur, segoff,
                     blk2_e, blk2_m0);
  hipLaunchKernelGGL(k_gemm1, dim3(16 * TMX2), dim3(512), 0, stream,
                     xbf, wt1, b1, assign, cur, segoff, blk2_e, blk2_m0, hbuf);
  hipLaunchKernelGGL(k_gemm2, dim3(8 * TMX2), dim3(512), 0, stream,
                     hbuf, wt2, b2, assign, cur, segoff, blk2_e, blk2_m0, contrib);
  hipLaunchKernelGGL(k_combine, dim3((BT * DIM / 4 + 255) / 256), dim3(256), 0, stream,
                     contrib, probs01, out);
}

// Round 3
// 529.598 us; speedup vs baseline: 1.0569x; 1.0569x over previous
//
#include <hip/hip_runtime.h>
#include <hip/hip_bf16.h>
#include <math.h>
#include <stdint.h>

#define BT  4096
#define DIM 1024
#define HID 4096
#define NE  8
#define TMX  72   // max active 128-row m-blocks (64 full + 8 partial)
#define TMX2 40   // max active 256-row m-blocks (32 full + 8 partial)

typedef __attribute__((ext_vector_type(8))) short short8v;
typedef __attribute__((ext_vector_type(4))) float f32x4;
typedef unsigned short ushort_t;

typedef __attribute__((address_space(1))) const void gas_void;
typedef __attribute__((address_space(3))) void las_void;
#define GLOAD_LDS16(g, l) __builtin_amdgcn_global_load_lds((gas_void*)(g), (las_void*)(l), 16, 0, 0)

__device__ inline ushort_t f2bf(float f) {
  __hip_bfloat16 b = __float2bfloat16(f);
  union { __hip_bfloat16 h; ushort_t u; } cv;
  cv.h = b;
  return cv.u;
}

// -------- prep: x fp32 -> bf16 ; zero per-expert cursors --------
__global__ void k_prep_x(const float* __restrict__ x, ushort_t* __restrict__ xbf,
                         int* __restrict__ cur) {
  if (blockIdx.x == 0 && threadIdx.x < NE) cur[threadIdx.x] = 0;
  int idx = blockIdx.x * blockDim.x + threadIdx.x;
  const int n4 = BT * DIM / 4;
  for (int i = idx; i < n4; i += gridDim.x * blockDim.x) {
    float4 v = ((const float4*)x)[i];
    ushort4 o;
    o.x = f2bf(v.x); o.y = f2bf(v.y); o.z = f2bf(v.z); o.w = f2bf(v.w);
    ((ushort4*)xbf)[i] = o;
  }
}

// -------- transpose+convert: src fp32 [E][R][C] -> dst bf16 [E][C][R] --------
__global__ __launch_bounds__(256) void k_transpose(const float* __restrict__ src,
                                                   ushort_t* __restrict__ dst,
                                                   int R, int C) {
  __shared__ float tile[64][65];
  int e = blockIdx.z;
  const float* s = src + (size_t)e * R * C;
  ushort_t* d = dst + (size_t)e * R * C;
  int c0 = blockIdx.x * 64, r0 = blockIdx.y * 64;
  int t = threadIdx.x;
  int lr = t >> 4;
  int lc4 = (t & 15) * 4;
#pragma unroll
  for (int i = 0; i < 4; i++) {
    int r = lr + 16 * i;
    float4 v = *(const float4*)&s[(size_t)(r0 + r) * C + c0 + lc4];
    tile[r][lc4 + 0] = v.x; tile[r][lc4 + 1] = v.y;
    tile[r][lc4 + 2] = v.z; tile[r][lc4 + 3] = v.w;
  }
  __syncthreads();
#pragma unroll
  for (int i = 0; i < 4; i++) {
    int c = lr + 16 * i;
    ushort4 o;
    o.x = f2bf(tile[lc4 + 0][c]);
    o.y = f2bf(tile[lc4 + 1][c]);
    o.z = f2bf(tile[lc4 + 2][c]);
    o.w = f2bf(tile[lc4 + 3][c]);
    *(ushort4*)&d[(size_t)(c0 + c) * R + r0 + lc4] = o;
  }
}

// -------- router: logits, softmax, top-2, binning --------
__global__ __launch_bounds__(64) void k_router(
    const float* __restrict__ x, const float* __restrict__ wg,
    float* __restrict__ logits_out, float* __restrict__ probs01,
    int* __restrict__ assign, int* __restrict__ cur) {
  int t = blockIdx.x;
  int lane = threadIdx.x;
  float part[NE];
#pragma unroll
  for (int e = 0; e < NE; e++) part[e] = 0.f;
  const float* xr = x + (size_t)t * DIM;
  for (int d = lane; d < DIM; d += 64) {
    float xv = xr[d];
    const float4* wr = (const float4*)(wg + (size_t)d * NE);
    float4 w0 = wr[0], w1v = wr[1];
    part[0] += xv * w0.x;  part[1] += xv * w0.y;
    part[2] += xv * w0.z;  part[3] += xv * w0.w;
    part[4] += xv * w1v.x; part[5] += xv * w1v.y;
    part[6] += xv * w1v.z; part[7] += xv * w1v.w;
  }
#pragma unroll
  for (int e = 0; e < NE; e++)
    for (int off = 32; off > 0; off >>= 1)
      part[e] += __shfl_xor(part[e], off);
  if (lane == 0) {
    float m = part[0];
    for (int e = 1; e < NE; e++) m = fmaxf(m, part[e]);
    float p[NE], s = 0.f;
    for (int e = 0; e < NE; e++) { p[e] = expf(part[e] - m); s += p[e]; }
    float inv = 1.f / s;
    for (int e = 0; e < NE; e++) p[e] *= inv;
    for (int e = 0; e < NE; e++) logits_out[(size_t)t * NE + e] = part[e];
    probs01[t * 2 + 0] = p[0];
    probs01[t * 2 + 1] = p[1];
    int b0 = 0;
    for (int e = 1; e < NE; e++) if (p[e] > p[b0]) b0 = e;
    int b1 = (b0 == 0) ? 1 : 0;
    for (int e = 0; e < NE; e++) if (e != b0 && p[e] > p[b1]) b1 = e;
    int pos0 = atomicAdd(&cur[b0], 1);
    assign[b0 * BT + pos0] = t * 2 + 0;
    int pos1 = atomicAdd(&cur[b1], 1);
    assign[b1 * BT + pos1] = t * 2 + 1;
  }
}

// -------- plan: prefix offsets + flattened active block lists (128 & 256) --------
__global__ void k_plan(const int* __restrict__ cur, int* __restrict__ segoff,
                       int* __restrict__ blk_e, int* __restrict__ blk_m0,
                       int* __restrict__ blk2_e, int* __restrict__ blk2_m0) {
  if (threadIdx.x == 0 && blockIdx.x == 0) {
    int s = 0;
    for (int e = 0; e < NE; e++) { segoff[e] = s; s += cur[e]; }
    int t = 0;
    for (int e = 0; e < NE; e++) {
      int mb = (cur[e] + 127) >> 7;
      for (int i = 0; i < mb; i++) { blk_e[t] = e; blk_m0[t] = i << 7; t++; }
    }
    for (; t < TMX; t++) { blk_e[t] = -1; blk_m0[t] = 0; }
    t = 0;
    for (int e = 0; e < NE; e++) {
      int mb = (cur[e] + 255) >> 8;
      for (int i = 0; i < mb; i++) { blk2_e[t] = e; blk2_m0[t] = i << 8; t++; }
    }
    for (; t < TMX2; t++) { blk2_e[t] = -1; blk2_m0[t] = 0; }
  }
}

// ============================================================================
// Swizzle note (64 B LDS rows, 4 x 16B units): bank = (16*(row&1) + 4*unit)%32,
// so only row bit 0 reaches the bank index. Store logical unit u of row r at
// physical u ^ ((r>>1)&3): rows 0..7 then enumerate all 8 bank-groups ->
// 8 dwords/bank per wave ds_read_b128 (the floor). Stage side: gload_lds lane l
// writes row base+(l>>2), physical unit l&3 -> source logical unit
// (l&3) ^ ((l>>3)&3). Read side: logical unit g=lane>>4 of row base+lr ->
// physical g ^ ((lr>>1)&3).
// ============================================================================

// ============================================================================
// GEMM1: h = gelu(x_gathered @ w1^T + b1)
// 256x256 tile, BK=32, 4-deep LDS ring (128 KiB), one barrier per K-tile,
// counted vmcnt, corrected swizzle, T5 setprio. Wave tile 128x64 (2M x 4N).
// ============================================================================
__global__ __launch_bounds__(512, 2) void k_gemm1(
    const ushort_t* __restrict__ xbf, const ushort_t* __restrict__ wt1,
    const float* __restrict__ b1,
    const int* __restrict__ assign, const int* __restrict__ cur,
    const int* __restrict__ segoff, const int* __restrict__ blk2_e,
    const int* __restrict__ blk2_m0, ushort_t* __restrict__ hbuf) {
  const int nwg = 16 * TMX2;                   // 640, divisible by 8
  int f = blockIdx.x;
  int lg = (f & 7) * (nwg >> 3) + (f >> 3);    // XCD chunk swizzle (bijective)
  int m_idx = lg % TMX2;                       // m-inner: chunk reuses B-panels
  int n_idx = lg / TMX2;
  int e = blk2_e[m_idx];
  if (e < 0) return;
  int m0 = blk2_m0[m_idx];
  int count = cur[e];
  int n0 = n_idx << 8;

  __shared__ __attribute__((aligned(16))) ushort_t A[4][256][32];
  __shared__ __attribute__((aligned(16))) ushort_t Bv[4][256][32];
  int tid = threadIdx.x;
  int lane = tid & 63, wid = tid >> 6;

  int srow = lane >> 2;
  int sunit = ((lane & 3) ^ ((lane >> 3) & 3)) << 3;   // corrected stage swizzle
  int pA0 = m0 + wid * 16 + srow;
  int pA1 = pA0 + 128;
  int tok0 = (pA0 < count) ? (assign[e * BT + pA0] >> 1) : 0;
  int tok1 = (pA1 < count) ? (assign[e * BT + pA1] >> 1) : 0;
  const ushort_t* gA0 = xbf + (size_t)tok0 * DIM + sunit;
  const ushort_t* gA1 = xbf + (size_t)tok1 * DIM + sunit;
  const ushort_t* gB0 = wt1 + ((size_t)e * HID + n0 + wid * 16 + srow) * DIM + sunit;
  const ushort_t* gB1 = gB0 + (size_t)128 * DIM;

  int wm = wid >> 2, wn = wid & 3;             // wave tile: 128(m) x 64(n)
  int lr = lane & 15, g = lane >> 4;
  int xsw = ((g ^ ((lr >> 1) & 3)) << 3);      // corrected read swizzle
  f32x4 acc[8][4];
  f32x4 zero = {0.f, 0.f, 0.f, 0.f};
#pragma unroll
  for (int m = 0; m < 8; m++)
#pragma unroll
    for (int n = 0; n < 4; n++) acc[m][n] = zero;

#define STAGE1(TB, K0)                                         \
  { GLOAD_LDS16(gA0 + (K0), &A[TB][wid * 16][0]);              \
    GLOAD_LDS16(gA1 + (K0), &A[TB][128 + wid * 16][0]);        \
    GLOAD_LDS16(gB0 + (K0), &Bv[TB][wid * 16][0]);             \
    GLOAD_LDS16(gB1 + (K0), &Bv[TB][128 + wid * 16][0]); }

#define BODY1(T, TB, VM, DOSTAGE)                                              \
  { asm volatile("s_waitcnt vmcnt(" #VM ")" ::: "memory");                     \
    __builtin_amdgcn_s_barrier();                                              \
    __builtin_amdgcn_sched_barrier(0);                                         \
    if (DOSTAGE) { STAGE1((((TB) + 3) & 3), ((T) + 3) * 32); }                 \
    short8v af[8], bfv[4];                                                     \
    _Pragma("unroll")                                                          \
    for (int m = 0; m < 8; m++)                                                \
      af[m] = *(const short8v*)&A[TB][wm * 128 + m * 16 + lr][xsw];            \
    _Pragma("unroll")                                                          \
    for (int n = 0; n < 4; n++)                                                \
      bfv[n] = *(const short8v*)&Bv[TB][wn * 64 + n * 16 + lr][xsw];           \
    __builtin_amdgcn_s_setprio(1);                                             \
    _Pragma("unroll")                                                          \
    for (int m = 0; m < 8; m++)                                                \
      _Pragma("unroll")                                                        \
      for (int n = 0; n < 4; n++)                                              \
        acc[m][n] = __builtin_amdgcn_mfma_f32_16x16x32_bf16(af[m], bfv[n],     \
                                                            acc[m][n], 0, 0, 0); \
    __builtin_amdgcn_s_setprio(0); }

  STAGE1(0, 0);
  STAGE1(1, 32);
  STAGE1(2, 64);
  const int NT = DIM / 32;                     // 32
  for (int t = 0; t < NT - 4; t += 4) {
    BODY1(t + 0, 0, 8, 1);
    BODY1(t + 1, 1, 8, 1);
    BODY1(t + 2, 2, 8, 1);
    BODY1(t + 3, 3, 8, 1);
  }
  BODY1(NT - 4, 0, 8, 1);
  BODY1(NT - 3, 1, 8, 0);
  BODY1(NT - 2, 2, 4, 0);
  BODY1(NT - 1, 3, 0, 0);
#undef STAGE1
#undef BODY1

  int so = segoff[e];
#pragma unroll
  for (int m = 0; m < 8; m++) {
#pragma unroll
    for (int j = 0; j < 4; j++) {
      int p = m0 + wm * 128 + m * 16 + g * 4 + j;
      if (p >= count) continue;
      ushort_t* hr = hbuf + (size_t)(so + p) * HID;
#pragma unroll
      for (int n = 0; n < 4; n++) {
        int col = n0 + wn * 64 + n * 16 + lr;
        float v = acc[m][n][j] + b1[e * HID + col];
        float gl = 0.5f * v * (1.0f + erff(v * 0.70710678118654752f));
        hr[col] = f2bf(gl);
      }
    }
  }
}

// ============================================================================
// GEMM2: contrib[slot][t] = h @ w2^T + b2
// 128x256 tile, BK=32, 4-deep LDS ring (96 KiB), counted vmcnt.
// 8 waves as 2M x 4N (wave tile 64x64). 3 gloads/tile -> vmcnt(6) steady.
// 288 blocks (1.1 rounds); m-inner XCD chunks keep the 2MB B-panel L2-resident.
// ============================================================================
__global__ __launch_bounds__(512, 2) void k_gemm2(
    const ushort_t* __restrict__ hbuf, const ushort_t* __restrict__ wt2,
    const float* __restrict__ b2,
    const int* __restrict__ assign, const int* __restrict__ cur,
    const int* __restrict__ segoff, const int* __restrict__ blk_e,
    const int* __restrict__ blk_m0, float* __restrict__ contrib) {
  const int nwg = 4 * TMX;                     // 288, divisible by 8
  int f = blockIdx.x;
  int lg = (f & 7) * (nwg >> 3) + (f >> 3);
  int m_idx = lg % TMX;                        // m-inner: chunk reuses B-panel
  int n_idx = lg / TMX;
  int e = blk_e[m_idx];
  if (e < 0) return;
  int m0 = blk_m0[m_idx];
  int count = cur[e];
  int n0 = n_idx << 8;
  int so = segoff[e];

  __shared__ __attribute__((aligned(16))) ushort_t A[4][128][32];
  __shared__ __attribute__((aligned(16))) ushort_t Bv[4][256][32];
  int tid = threadIdx.x;
  int lane = tid & 63, wid = tid >> 6;

  int srow = lane >> 2;
  int sunit = ((lane & 3) ^ ((lane >> 3) & 3)) << 3;
  int pA0 = m0 + wid * 16 + srow;
  int pa0 = (pA0 < count) ? pA0 : (count - 1);
  const ushort_t* gA0 = hbuf + (size_t)(so + pa0) * HID + sunit;
  const ushort_t* gB0 = wt2 + ((size_t)e * DIM + n0 + wid * 16 + srow) * HID + sunit;
  const ushort_t* gB1 = gB0 + (size_t)128 * HID;

  int wm = wid >> 2, wn = wid & 3;             // wave tile: 64(m) x 64(n)
  int lr = lane & 15, g = lane >> 4;
  int xsw = ((g ^ ((lr >> 1) & 3)) << 3);
  f32x4 acc[4][4];
  f32x4 zero = {0.f, 0.f, 0.f, 0.f};
#pragma unroll
  for (int m = 0; m < 4; m++)
#pragma unroll
    for (int n = 0; n < 4; n++) acc[m][n] = zero;

#define STAGE2(TB, K0)                                         \
  { GLOAD_LDS16(gA0 + (K0), &A[TB][wid * 16][0]);              \
    GLOAD_LDS16(gB0 + (K0), &Bv[TB][wid * 16][0]);             \
    GLOAD_LDS16(gB1 + (K0), &Bv[TB][128 + wid * 16][0]); }

#define BODY2(T, TB, VM, DOSTAGE)                                              \
  { asm volatile("s_waitcnt vmcnt(" #VM ")" ::: "memory");                     \
    __builtin_amdgcn_s_barrier();                                              \
    __builtin_amdgcn_sched_barrier(0);                                         \
    if (DOSTAGE) { STAGE2((((TB) + 3) & 3), ((T) + 3) * 32); }                 \
    short8v af[4], bfv[4];                                                     \
    _Pragma("unroll")                                                          \
    for (int m = 0; m < 4; m++)                                                \
      af[m] = *(const short8v*)&A[TB][wm * 64 + m * 16 + lr][xsw];             \
    _Pragma("unroll")                                                          \
    for (int n = 0; n < 4; n++)                                                \
      bfv[n] = *(const short8v*)&Bv[TB][wn * 64 + n * 16 + lr][xsw];           \
    __builtin_amdgcn_s_setprio(1);                                             \
    _Pragma("unroll")                                                          \
    for (int m = 0; m < 4; m++)                                                \
      _Pragma("unroll")                                                        \
      for (int n = 0; n < 4; n++)                                              \
        acc[m][n] = __builtin_amdgcn_mfma_f32_16x16x32_bf16(af[m], bfv[n],     \
                                                            acc[m][n], 0, 0, 0); \
    __builtin_amdgcn_s_setprio(0); }

  STAGE2(0, 0);
  STAGE2(1, 32);
  STAGE2(2, 64);
  const int NT = HID / 32;                     // 128
  for (int t = 0; t < NT - 4; t += 4) {
    BODY2(t + 0, 0, 6, 1);
    BODY2(t + 1, 1, 6, 1);
    BODY2(t + 2, 2, 6, 1);
    BODY2(t + 3, 3, 6, 1);
  }
  BODY2(NT - 4, 0, 6, 1);
  BODY2(NT - 3, 1, 6, 0);
  BODY2(NT - 2, 2, 3, 0);
  BODY2(NT - 1, 3, 0, 0);
#undef STAGE2
#undef BODY2

#pragma unroll
  for (int m = 0; m < 4; m++) {
#pragma unroll
    for (int j = 0; j < 4; j++) {
      int p = m0 + wm * 64 + m * 16 + g * 4 + j;
      if (p >= count) continue;
      int a = assign[e * BT + p];
      int t = a >> 1, slot = a & 1;
      float* cr = contrib + ((size_t)slot * BT + t) * DIM;
#pragma unroll
      for (int n = 0; n < 4; n++) {
        int col = n0 + wn * 64 + n * 16 + lr;
        cr[col] = acc[m][n][j] + b2[e * DIM + col];
      }
    }
  }
}

// -------- combine: final = c0*probs[:,0] + c1*probs[:,1] --------
__global__ void k_combine(const float* __restrict__ contrib,
                          const float* __restrict__ probs01,
                          float* __restrict__ out) {
  int idx = blockIdx.x * blockDim.x + threadIdx.x;
  const int n4 = BT * DIM / 4;
  if (idx >= n4) return;
  int t = idx >> 8;
  float wA = probs01[t * 2 + 0], wB = probs01[t * 2 + 1];
  float4 c0 = ((const float4*)contrib)[idx];
  float4 c1 = ((const float4*)(contrib + (size_t)BT * DIM))[idx];
  float4 o;
  o.x = c0.x * wA + c1.x * wB;
  o.y = c0.y * wA + c1.y * wB;
  o.z = c0.z * wA + c1.z * wB;
  o.w = c0.w * wA + c1.w * wB;
  ((float4*)out)[idx] = o;
}

extern "C" void kernel_launch(void* const* d_in, const int* in_sizes, int n_in,
                              void* d_out, int out_size, void* d_ws, size_t ws_size,
                              hipStream_t stream) {
  const float* x  = (const float*)d_in[0];
  const float* wg = (const float*)d_in[1];
  const float* w1 = (const float*)d_in[2];
  const float* b1 = (const float*)d_in[3];
  const float* w2 = (const float*)d_in[4];
  const float* b2 = (const float*)d_in[5];
  float* out = (float*)d_out;
  float* logits_out = out + (size_t)BT * DIM;

  char* ws = (char*)d_ws;
  size_t off = 0;
  auto alloc = [&](size_t bytes) -> void* {
    void* p = ws + off;
    off = (off + bytes + 255) & ~(size_t)255;
    return p;
  };
  ushort_t* xbf    = (ushort_t*)alloc((size_t)BT * DIM * 2);
  ushort_t* wt1    = (ushort_t*)alloc((size_t)NE * HID * DIM * 2);
  ushort_t* wt2    = (ushort_t*)alloc((size_t)NE * DIM * HID * 2);
  ushort_t* hbuf   = (ushort_t*)alloc((size_t)2 * BT * HID * 2);
  float*    contrib= (float*)alloc((size_t)2 * BT * DIM * 4);
  float*    probs01= (float*)alloc((size_t)BT * 2 * 4);
  int*      assign = (int*)alloc((size_t)NE * BT * 4);
  int*      cur    = (int*)alloc(64);
  int*      segoff = (int*)alloc(64);
  int*      blk_e  = (int*)alloc(TMX * 4);
  int*      blk_m0 = (int*)alloc(TMX * 4);
  int*      blk2_e = (int*)alloc(TMX2 * 4);
  int*      blk2_m0= (int*)alloc(TMX2 * 4);
  if (off > ws_size) return;

  hipLaunchKernelGGL(k_prep_x, dim3(1024), dim3(256), 0, stream, x, xbf, cur);
  hipLaunchKernelGGL(k_transpose, dim3(HID / 64, DIM / 64, NE), dim3(256), 0, stream,
                     w1, wt1, DIM, HID);
  hipLaunchKernelGGL(k_transpose, dim3(DIM / 64, HID / 64, NE), dim3(256), 0, stream,
                     w2, wt2, HID, DIM);
  hipLaunchKernelGGL(k_router, dim3(BT), dim3(64), 0, stream,
                     x, wg, logits_out, probs01, assign, cur);
  hipLaunchKernelGGL(k_plan, dim3(1), dim3(1), 0, stream, cur, segoff,
                     blk_e, blk_m0, blk2_e, blk2_m0);
  hipLaunchKernelGGL(k_gemm1, dim3(16 * TMX2), dim3(512), 0, stream,
                     xbf, wt1, b1, assign, cur, segoff, blk2_e, blk2_m0, hbuf);
  hipLaunchKernelGGL(k_gemm2, dim3(4 * TMX), dim3(512), 0, stream,
                     hbuf, wt2, b2, assign, cur, segoff, blk_e, blk_m0, contrib);
  hipLaunchKernelGGL(k_combine, dim3((BT * DIM / 4 + 255) / 256), dim3(256), 0, stream,
                     contrib, probs01, out);
}

// Round 4
// 497.485 us; speedup vs baseline: 1.1251x; 1.0646x over previous
//
#include <hip/hip_runtime.h>
#include <hip/hip_bf16.h>
#include <math.h>
#include <stdint.h>

#define BT  4096
#define DIM 1024
#define HID 4096
#define NE  8
#define TMX2 40   // max active 256-row m-blocks (32 full + 8 partial)

typedef __attribute__((ext_vector_type(8))) short short8v;
typedef __attribute__((ext_vector_type(4))) float f32x4;
typedef unsigned short ushort_t;

typedef __attribute__((address_space(1))) const void gas_void;
typedef __attribute__((address_space(3))) void las_void;
#define GLOAD_LDS16(g, l) __builtin_amdgcn_global_load_lds((gas_void*)(g), (las_void*)(l), 16, 0, 0)

__device__ inline ushort_t f2bf(float f) {
  __hip_bfloat16 b = __float2bfloat16(f);
  union { __hip_bfloat16 h; ushort_t u; } cv;
  cv.h = b;
  return cv.u;
}

// -------- prep: x fp32 -> bf16 ; zero per-expert cursors --------
__global__ void k_prep_x(const float* __restrict__ x, ushort_t* __restrict__ xbf,
                         int* __restrict__ cur) {
  if (blockIdx.x == 0 && threadIdx.x < NE) cur[threadIdx.x] = 0;
  int idx = blockIdx.x * blockDim.x + threadIdx.x;
  const int n4 = BT * DIM / 4;
  for (int i = idx; i < n4; i += gridDim.x * blockDim.x) {
    float4 v = ((const float4*)x)[i];
    ushort4 o;
    o.x = f2bf(v.x); o.y = f2bf(v.y); o.z = f2bf(v.z); o.w = f2bf(v.w);
    ((ushort4*)xbf)[i] = o;
  }
}

// -------- transpose+convert: src fp32 [E][R][C] -> dst bf16 [E][C][R] --------
__global__ __launch_bounds__(256) void k_transpose(const float* __restrict__ src,
                                                   ushort_t* __restrict__ dst,
                                                   int R, int C) {
  __shared__ float tile[64][65];
  int e = blockIdx.z;
  const float* s = src + (size_t)e * R * C;
  ushort_t* d = dst + (size_t)e * R * C;
  int c0 = blockIdx.x * 64, r0 = blockIdx.y * 64;
  int t = threadIdx.x;
  int lr = t >> 4;
  int lc4 = (t & 15) * 4;
#pragma unroll
  for (int i = 0; i < 4; i++) {
    int r = lr + 16 * i;
    float4 v = *(const float4*)&s[(size_t)(r0 + r) * C + c0 + lc4];
    tile[r][lc4 + 0] = v.x; tile[r][lc4 + 1] = v.y;
    tile[r][lc4 + 2] = v.z; tile[r][lc4 + 3] = v.w;
  }
  __syncthreads();
#pragma unroll
  for (int i = 0; i < 4; i++) {
    int c = lr + 16 * i;
    ushort4 o;
    o.x = f2bf(tile[lc4 + 0][c]);
    o.y = f2bf(tile[lc4 + 1][c]);
    o.z = f2bf(tile[lc4 + 2][c]);
    o.w = f2bf(tile[lc4 + 3][c]);
    *(ushort4*)&d[(size_t)(c0 + c) * R + r0 + lc4] = o;
  }
}

// -------- router: logits, softmax, top-2, binning --------
__global__ __launch_bounds__(64) void k_router(
    const float* __restrict__ x, const float* __restrict__ wg,
    float* __restrict__ logits_out, float* __restrict__ probs01,
    int* __restrict__ assign, int* __restrict__ cur) {
  int t = blockIdx.x;
  int lane = threadIdx.x;
  float part[NE];
#pragma unroll
  for (int e = 0; e < NE; e++) part[e] = 0.f;
  const float* xr = x + (size_t)t * DIM;
  for (int d = lane; d < DIM; d += 64) {
    float xv = xr[d];
    const float4* wr = (const float4*)(wg + (size_t)d * NE);
    float4 w0 = wr[0], w1v = wr[1];
    part[0] += xv * w0.x;  part[1] += xv * w0.y;
    part[2] += xv * w0.z;  part[3] += xv * w0.w;
    part[4] += xv * w1v.x; part[5] += xv * w1v.y;
    part[6] += xv * w1v.z; part[7] += xv * w1v.w;
  }
#pragma unroll
  for (int e = 0; e < NE; e++)
    for (int off = 32; off > 0; off >>= 1)
      part[e] += __shfl_xor(part[e], off);
  if (lane == 0) {
    float m = part[0];
    for (int e = 1; e < NE; e++) m = fmaxf(m, part[e]);
    float p[NE], s = 0.f;
    for (int e = 0; e < NE; e++) { p[e] = expf(part[e] - m); s += p[e]; }
    float inv = 1.f / s;
    for (int e = 0; e < NE; e++) p[e] *= inv;
    for (int e = 0; e < NE; e++) logits_out[(size_t)t * NE + e] = part[e];
    probs01[t * 2 + 0] = p[0];
    probs01[t * 2 + 1] = p[1];
    int b0 = 0;
    for (int e = 1; e < NE; e++) if (p[e] > p[b0]) b0 = e;
    int b1 = (b0 == 0) ? 1 : 0;
    for (int e = 0; e < NE; e++) if (e != b0 && p[e] > p[b1]) b1 = e;
    int pos0 = atomicAdd(&cur[b0], 1);
    assign[b0 * BT + pos0] = t * 2 + 0;
    int pos1 = atomicAdd(&cur[b1], 1);
    assign[b1 * BT + pos1] = t * 2 + 1;
  }
}

// -------- plan: prefix offsets + flattened active 256-row block list --------
__global__ void k_plan(const int* __restrict__ cur, int* __restrict__ segoff,
                       int* __restrict__ blk2_e, int* __restrict__ blk2_m0) {
  if (threadIdx.x == 0 && blockIdx.x == 0) {
    int s = 0;
    for (int e = 0; e < NE; e++) { segoff[e] = s; s += cur[e]; }
    int t = 0;
    for (int e = 0; e < NE; e++) {
      int mb = (cur[e] + 255) >> 8;
      for (int i = 0; i < mb; i++) { blk2_e[t] = e; blk2_m0[t] = i << 8; t++; }
    }
    for (; t < TMX2; t++) { blk2_e[t] = -1; blk2_m0[t] = 0; }
  }
}

// ============================================================================
// Shared K-tile body for both GEMMs (256x256 tile, BK=32, ring-4 LDS 128 KiB,
// 8 waves as 2M x 4N, wave tile 128x64, acc[8][4]).
// Per K-tile: TWO phases, each {ds_reads -> stage-unit -> [vmcnt] -> barrier
// -> setprio -> 16 MFMA}. Reads are issued BEFORE the barrier so the barrier
// wait absorbs ds_read latency. Staging is staggered: F2S = B-calls of tile
// t+3 issued in P1(t); L2S = A-calls of tile t+2 issued in P0(t).
// Boundary vmcnt(6) at end of P1(t) drains f2(t+1)+l2(t+1) (oldest 4 of 10
// outstanding) => tile t+1 block-visible after the barrier. Tail: 6,6,4,0.
// Slot safety (ring-4): stage of t+3 -> slot (t-1)&3; every wave lgkm-drained
// its t-1 reads before the P0(t) barrier that precedes the stage issue.
// ============================================================================
#define VM6 asm volatile("s_waitcnt vmcnt(6)" ::: "memory")
#define VM4 asm volatile("s_waitcnt vmcnt(4)" ::: "memory")
#define VM0 asm volatile("s_waitcnt vmcnt(0)" ::: "memory")
#define VMN do {} while (0)

#define TILEK(TB, T, VMX, DOL2, DOF2)                                           \
  { short8v bv[4], afl[4];                                                      \
    _Pragma("unroll")                                                           \
    for (int n = 0; n < 4; n++)                                                 \
      bv[n] = *(const short8v*)&Bv[TB][wn * 64 + n * 16 + lr][xsw];             \
    _Pragma("unroll")                                                           \
    for (int m = 0; m < 4; m++)                                                 \
      afl[m] = *(const short8v*)&A[TB][wm * 128 + m * 16 + lr][xsw];            \
    if (DOL2) { L2S((((TB) + 2) & 3), ((T) + 2) * 32); }                        \
    __builtin_amdgcn_s_barrier();                                               \
    __builtin_amdgcn_sched_barrier(0);                                          \
    __builtin_amdgcn_s_setprio(1);                                              \
    _Pragma("unroll")                                                           \
    for (int m = 0; m < 4; m++)                                                 \
      _Pragma("unroll")                                                         \
      for (int n = 0; n < 4; n++)                                               \
        acc[m][n] = __builtin_amdgcn_mfma_f32_16x16x32_bf16(afl[m], bv[n],      \
                                                            acc[m][n], 0, 0, 0);\
    __builtin_amdgcn_s_setprio(0);                                              \
    short8v afh[4];                                                             \
    _Pragma("unroll")                                                           \
    for (int m = 0; m < 4; m++)                                                 \
      afh[m] = *(const short8v*)&A[TB][wm * 128 + 64 + m * 16 + lr][xsw];       \
    if (DOF2) { F2S((((TB) + 3) & 3), ((T) + 3) * 32); }                        \
    VMX;                                                                        \
    __builtin_amdgcn_s_barrier();                                               \
    __builtin_amdgcn_sched_barrier(0);                                          \
    __builtin_amdgcn_s_setprio(1);                                              \
    _Pragma("unroll")                                                           \
    for (int m = 0; m < 4; m++)                                                 \
      _Pragma("unroll")                                                         \
      for (int n = 0; n < 4; n++)                                               \
        acc[4 + m][n] = __builtin_amdgcn_mfma_f32_16x16x32_bf16(afh[m], bv[n],  \
                                                        acc[4 + m][n], 0, 0, 0);\
    __builtin_amdgcn_s_setprio(0); }

// ============================================================================
// GEMM1: h = gelu(x_gathered @ w1^T + b1).  Grid 16*TMX2 = 640.
// ============================================================================
__global__ __launch_bounds__(512, 2) void k_gemm1(
    const ushort_t* __restrict__ xbf, const ushort_t* __restrict__ wt1,
    const float* __restrict__ b1,
    const int* __restrict__ assign, const int* __restrict__ cur,
    const int* __restrict__ segoff, const int* __restrict__ blk2_e,
    const int* __restrict__ blk2_m0, ushort_t* __restrict__ hbuf) {
  const int nwg = 16 * TMX2;                   // 640, divisible by 8
  int f = blockIdx.x;
  int lg = (f & 7) * (nwg >> 3) + (f >> 3);    // XCD chunk swizzle (bijective)
  int m_idx = lg % TMX2;                       // m-inner: chunk reuses B-panels
  int n_idx = lg / TMX2;
  int e = blk2_e[m_idx];
  if (e < 0) return;
  int m0 = blk2_m0[m_idx];
  int count = cur[e];
  int n0 = n_idx << 8;

  __shared__ __attribute__((aligned(16))) ushort_t A[4][256][32];
  __shared__ __attribute__((aligned(16))) ushort_t Bv[4][256][32];
  int tid = threadIdx.x;
  int lane = tid & 63, wid = tid >> 6;

  int srow = lane >> 2;
  int sunit = ((lane & 3) ^ ((lane >> 3) & 3)) << 3;
  int pA0 = m0 + wid * 16 + srow;
  int pA1 = pA0 + 128;
  int tok0 = (pA0 < count) ? (assign[e * BT + pA0] >> 1) : 0;
  int tok1 = (pA1 < count) ? (assign[e * BT + pA1] >> 1) : 0;
  const ushort_t* gA0 = xbf + (size_t)tok0 * DIM + sunit;
  const ushort_t* gA1 = xbf + (size_t)tok1 * DIM + sunit;
  const ushort_t* gB0 = wt1 + ((size_t)e * HID + n0 + wid * 16 + srow) * DIM + sunit;
  const ushort_t* gB1 = gB0 + (size_t)128 * DIM;

  int wm = wid >> 2, wn = wid & 3;             // wave tile: 128(m) x 64(n)
  int lr = lane & 15, g = lane >> 4;
  int xsw = ((g ^ ((lr >> 1) & 3)) << 3);
  f32x4 acc[8][4];
  f32x4 zero = {0.f, 0.f, 0.f, 0.f};
#pragma unroll
  for (int m = 0; m < 8; m++)
#pragma unroll
    for (int n = 0; n < 4; n++) acc[m][n] = zero;

#define F2S(SL, K0)                                            \
  { GLOAD_LDS16(gB0 + (K0), &Bv[SL][wid * 16][0]);             \
    GLOAD_LDS16(gB1 + (K0), &Bv[SL][128 + wid * 16][0]); }
#define L2S(SL, K0)                                            \
  { GLOAD_LDS16(gA0 + (K0), &A[SL][wid * 16][0]);              \
    GLOAD_LDS16(gA1 + (K0), &A[SL][128 + wid * 16][0]); }

  // prologue: f2(0), l2(0), f2(1), l2(1), f2(2) -> 10 loads; drain tile 0
  F2S(0, 0);  L2S(0, 0);
  F2S(1, 32); L2S(1, 32);
  F2S(2, 64);
  VM6;
  __builtin_amdgcn_s_barrier();
  __builtin_amdgcn_sched_barrier(0);

  const int NT = DIM / 32;                     // 32
  for (int t = 0; t < NT - 4; t += 4) {
    TILEK(0, t + 0, VM6, 1, 1);
    TILEK(1, t + 1, VM6, 1, 1);
    TILEK(2, t + 2, VM6, 1, 1);
    TILEK(3, t + 3, VM6, 1, 1);
  }
  TILEK(0, NT - 4, VM6, 1, 1);
  TILEK(1, NT - 3, VM4, 1, 0);
  TILEK(2, NT - 2, VM0, 0, 0);
  TILEK(3, NT - 1, VMN, 0, 0);
#undef F2S
#undef L2S

  int so = segoff[e];
#pragma unroll
  for (int m = 0; m < 8; m++) {
#pragma unroll
    for (int j = 0; j < 4; j++) {
      int p = m0 + wm * 128 + m * 16 + g * 4 + j;
      if (p >= count) continue;
      ushort_t* hr = hbuf + (size_t)(so + p) * HID;
#pragma unroll
      for (int n = 0; n < 4; n++) {
        int col = n0 + wn * 64 + n * 16 + lr;
        float v = acc[m][n][j] + b1[e * HID + col];
        float gl = 0.5f * v * (1.0f + erff(v * 0.70710678118654752f));
        hr[col] = f2bf(gl);
      }
    }
  }
}

// ============================================================================
// GEMM2: contrib[slot][t] = h @ w2^T + b2.  256x256 tile, grid 4*TMX2 = 160.
// ============================================================================
__global__ __launch_bounds__(512, 2) void k_gemm2(
    const ushort_t* __restrict__ hbuf, const ushort_t* __restrict__ wt2,
    const float* __restrict__ b2,
    const int* __restrict__ assign, const int* __restrict__ cur,
    const int* __restrict__ segoff, const int* __restrict__ blk2_e,
    const int* __restrict__ blk2_m0, float* __restrict__ contrib) {
  const int nwg = 4 * TMX2;                    // 160, divisible by 8
  int f = blockIdx.x;
  int lg = (f & 7) * (nwg >> 3) + (f >> 3);
  int m_idx = lg % TMX2;
  int n_idx = lg / TMX2;
  int e = blk2_e[m_idx];
  if (e < 0) return;
  int m0 = blk2_m0[m_idx];
  int count = cur[e];
  int n0 = n_idx << 8;
  int so = segoff[e];

  __shared__ __attribute__((aligned(16))) ushort_t A[4][256][32];
  __shared__ __attribute__((aligned(16))) ushort_t Bv[4][256][32];
  int tid = threadIdx.x;
  int lane = tid & 63, wid = tid >> 6;

  int srow = lane >> 2;
  int sunit = ((lane & 3) ^ ((lane >> 3) & 3)) << 3;
  int pA0 = m0 + wid * 16 + srow;
  int pA1 = pA0 + 128;
  int pa0 = (pA0 < count) ? pA0 : (count - 1);
  int pa1 = (pA1 < count) ? pA1 : (count - 1);
  const ushort_t* gA0 = hbuf + (size_t)(so + pa0) * HID + sunit;
  const ushort_t* gA1 = hbuf + (size_t)(so + pa1) * HID + sunit;
  const ushort_t* gB0 = wt2 + ((size_t)e * DIM + n0 + wid * 16 + srow) * HID + sunit;
  const ushort_t* gB1 = gB0 + (size_t)128 * HID;

  int wm = wid >> 2, wn = wid & 3;             // wave tile: 128(m) x 64(n)
  int lr = lane & 15, g = lane >> 4;
  int xsw = ((g ^ ((lr >> 1) & 3)) << 3);
  f32x4 acc[8][4];
  f32x4 zero = {0.f, 0.f, 0.f, 0.f};
#pragma unroll
  for (int m = 0; m < 8; m++)
#pragma unroll
    for (int n = 0; n < 4; n++) acc[m][n] = zero;

#define F2S(SL, K0)                                            \
  { GLOAD_LDS16(gB0 + (K0), &Bv[SL][wid * 16][0]);             \
    GLOAD_LDS16(gB1 + (K0), &Bv[SL][128 + wid * 16][0]); }
#define L2S(SL, K0)                                            \
  { GLOAD_LDS16(gA0 + (K0), &A[SL][wid * 16][0]);              \
    GLOAD_LDS16(gA1 + (K0), &A[SL][128 + wid * 16][0]); }

  F2S(0, 0);  L2S(0, 0);
  F2S(1, 32); L2S(1, 32);
  F2S(2, 64);
  VM6;
  __builtin_amdgcn_s_barrier();
  __builtin_amdgcn_sched_barrier(0);

  const int NT = HID / 32;                     // 128
  for (int t = 0; t < NT - 4; t += 4) {
    TILEK(0, t + 0, VM6, 1, 1);
    TILEK(1, t + 1, VM6, 1, 1);
    TILEK(2, t + 2, VM6, 1, 1);
    TILEK(3, t + 3, VM6, 1, 1);
  }
  TILEK(0, NT - 4, VM6, 1, 1);
  TILEK(1, NT - 3, VM4, 1, 0);
  TILEK(2, NT - 2, VM0, 0, 0);
  TILEK(3, NT - 1, VMN, 0, 0);
#undef F2S
#undef L2S

#pragma unroll
  for (int m = 0; m < 8; m++) {
#pragma unroll
    for (int j = 0; j < 4; j++) {
      int p = m0 + wm * 128 + m * 16 + g * 4 + j;
      if (p >= count) continue;
      int a = assign[e * BT + p];
      int t = a >> 1, slot = a & 1;
      float* cr = contrib + ((size_t)slot * BT + t) * DIM;
#pragma unroll
      for (int n = 0; n < 4; n++) {
        int col = n0 + wn * 64 + n * 16 + lr;
        cr[col] = acc[m][n][j] + b2[e * DIM + col];
      }
    }
  }
}

// -------- combine: final = c0*probs[:,0] + c1*probs[:,1] --------
__global__ void k_combine(const float* __restrict__ contrib,
                          const float* __restrict__ probs01,
                          float* __restrict__ out) {
  int idx = blockIdx.x * blockDim.x + threadIdx.x;
  const int n4 = BT * DIM / 4;
  if (idx >= n4) return;
  int t = idx >> 8;
  float wA = probs01[t * 2 + 0], wB = probs01[t * 2 + 1];
  float4 c0 = ((const float4*)contrib)[idx];
  float4 c1 = ((const float4*)(contrib + (size_t)BT * DIM))[idx];
  float4 o;
  o.x = c0.x * wA + c1.x * wB;
  o.y = c0.y * wA + c1.y * wB;
  o.z = c0.z * wA + c1.z * wB;
  o.w = c0.w * wA + c1.w * wB;
  ((float4*)out)[idx] = o;
}

extern "C" void kernel_launch(void* const* d_in, const int* in_sizes, int n_in,
                              void* d_out, int out_size, void* d_ws, size_t ws_size,
                              hipStream_t stream) {
  const float* x  = (const float*)d_in[0];
  const float* wg = (const float*)d_in[1];
  const float* w1 = (const float*)d_in[2];
  const float* b1 = (const float*)d_in[3];
  const float* w2 = (const float*)d_in[4];
  const float* b2 = (const float*)d_in[5];
  float* out = (float*)d_out;
  float* logits_out = out + (size_t)BT * DIM;

  char* ws = (char*)d_ws;
  size_t off = 0;
  auto alloc = [&](size_t bytes) -> void* {
    void* p = ws + off;
    off = (off + bytes + 255) & ~(size_t)255;
    return p;
  };
  ushort_t* xbf    = (ushort_t*)alloc((size_t)BT * DIM * 2);
  ushort_t* wt1    = (ushort_t*)alloc((size_t)NE * HID * DIM * 2);
  ushort_t* wt2    = (ushort_t*)alloc((size_t)NE * DIM * HID * 2);
  ushort_t* hbuf   = (ushort_t*)alloc((size_t)2 * BT * HID * 2);
  float*    contrib= (float*)alloc((size_t)2 * BT * DIM * 4);
  float*    probs01= (float*)alloc((size_t)BT * 2 * 4);
  int*      assign = (int*)alloc((size_t)NE * BT * 4);
  int*      cur    = (int*)alloc(64);
  int*      segoff = (int*)alloc(64);
  int*      blk2_e = (int*)alloc(TMX2 * 4);
  int*      blk2_m0= (int*)alloc(TMX2 * 4);
  if (off > ws_size) return;

  hipLaunchKernelGGL(k_prep_x, dim3(1024), dim3(256), 0, stream, x, xbf, cur);
  hipLaunchKernelGGL(k_transpose, dim3(HID / 64, DIM / 64, NE), dim3(256), 0, stream,
                     w1, wt1, DIM, HID);
  hipLaunchKernelGGL(k_transpose, dim3(DIM / 64, HID / 64, NE), dim3(256), 0, stream,
                     w2, wt2, HID, DIM);
  hipLaunchKernelGGL(k_router, dim3(BT), dim3(64), 0, stream,
                     x, wg, logits_out, probs01, assign, cur);
  hipLaunchKernelGGL(k_plan, dim3(1), dim3(1), 0, stream, cur, segoff,
                     blk2_e, blk2_m0);
  hipLaunchKernelGGL(k_gemm1, dim3(16 * TMX2), dim3(512), 0, stream,
                     xbf, wt1, b1, assign, cur, segoff, blk2_e, blk2_m0, hbuf);
  hipLaunchKernelGGL(k_gemm2, dim3(4 * TMX2), dim3(512), 0, stream,
                     hbuf, wt2, b2, assign, cur, segoff, blk2_e, blk2_m0, contrib);
  hipLaunchKernelGGL(k_combine, dim3((BT * DIM / 4 + 255) / 256), dim3(256), 0, stream,
                     contrib, probs01, out);
}